// Round 5
// baseline (545.410 us; speedup 1.0000x reference)
//
#include <hip/hip_runtime.h>

#define HID 64
#define NCLS 16
#define NCENT 3
#define NCENTS (NCLS * NCENT)
#define NBIN 16
#define BSHIFT 13   // 8192 nodes per bin; supports N <= 131072
#define CHUNK 2048  // edges per k_bin block

static inline int ceil_div(int a, int b) { return (a + b - 1) / b; }

// ---- edge binning (counting-sort by dst>>BSHIFT) ------------------------

__global__ void k_count(const int* __restrict__ dst, int* __restrict__ binCnt, int E) {
    __shared__ int c[NBIN];
    if (threadIdx.x < NBIN) c[threadIdx.x] = 0;
    __syncthreads();
    int stride = gridDim.x * blockDim.x;
    for (int e = blockIdx.x * blockDim.x + threadIdx.x; e < E; e += stride)
        atomicAdd(&c[dst[e] >> BSHIFT], 1);
    __syncthreads();
    if (threadIdx.x < NBIN && c[threadIdx.x] > 0)
        atomicAdd(&binCnt[threadIdx.x], c[threadIdx.x]);
}

__global__ void k_binoff(const int* __restrict__ binCnt, int* __restrict__ binBase) {
    if (threadIdx.x == 0) {
        int a = 0;
        for (int i = 0; i < NBIN; i++) { binBase[i] = a; a += binCnt[i]; }
    }
}

// Stage CHUNK edges in LDS, pack by bin, copy out coalesced per-bin segments.
// Result: binned[] is partition-grouped -> all later scattered work has a
// small (<=512 KB) active window.
__global__ __launch_bounds__(256) void k_bin(const int* __restrict__ src,
                                             const int* __restrict__ dst,
                                             const int* __restrict__ binBase,
                                             int* __restrict__ binCur,
                                             int2* __restrict__ binned, int E) {
    __shared__ int cnt[NBIN], off[NBIN], gbase[NBIN], cur[NBIN];
    __shared__ int2 stage[CHUNK];
    const int c0 = blockIdx.x * CHUNK;
    const int tid = threadIdx.x;
    if (tid < NBIN) cnt[tid] = 0;
    __syncthreads();
    int sv[CHUNK / 256], dv[CHUNK / 256], pv[CHUNK / 256];
#pragma unroll
    for (int j = 0; j < CHUNK / 256; j++) {
        int e = c0 + j * 256 + tid;
        if (e < E) {
            sv[j] = src[e]; dv[j] = dst[e];
            pv[j] = dv[j] >> BSHIFT;
            atomicAdd(&cnt[pv[j]], 1);
        } else pv[j] = -1;
    }
    __syncthreads();
    if (tid == 0) { int a = 0; for (int i = 0; i < NBIN; i++) { off[i] = a; a += cnt[i]; } }
    __syncthreads();
    if (tid < NBIN) {
        cur[tid] = 0;
        gbase[tid] = cnt[tid] ? atomicAdd(&binCur[tid], cnt[tid]) : 0;
    }
    __syncthreads();
#pragma unroll
    for (int j = 0; j < CHUNK / 256; j++)
        if (pv[j] >= 0) {
            int pos = off[pv[j]] + atomicAdd(&cur[pv[j]], 1);
            stage[pos] = make_int2(sv[j], dv[j]);
        }
    __syncthreads();
    int tot = min(CHUNK, E - c0);
    for (int i = tid; i < tot; i += 256) {
        int2 v = stage[i];
        int b = v.y >> BSHIFT;
        binned[binBase[b] + gbase[b] + (i - off[b])] = v;
    }
}

// deg from partition-grouped edges: atomic window = 32 KB at a time.
__global__ void k_degb(const int2* __restrict__ binned, int* __restrict__ deg, int E) {
    int e = blockIdx.x * blockDim.x + threadIdx.x;
    if (e < E) atomicAdd(&deg[binned[e].y], 1);
}

// ---- exclusive scan of deg -> rs (node-ordered), plus dinv --------------

__global__ void k_scan1(const int* __restrict__ deg, int* __restrict__ bsum, int N) {
    __shared__ int ts[256];
    int t = threadIdx.x;
    int base = blockIdx.x * 1024 + t * 4;
    int s = 0;
#pragma unroll
    for (int j = 0; j < 4; j++) if (base + j < N) s += deg[base + j];
    ts[t] = s;
    __syncthreads();
    for (int off = 128; off > 0; off >>= 1) {
        if (t < off) ts[t] += ts[t + off];
        __syncthreads();
    }
    if (t == 0) bsum[blockIdx.x] = ts[0];
}

__global__ void k_scan2(int* __restrict__ bsum, int B) {
    __shared__ int ts[256];
    int t = threadIdx.x;
    int v = (t < B) ? bsum[t] : 0;
    ts[t] = v;
    __syncthreads();
    for (int off = 1; off < 256; off <<= 1) {
        int x = (t >= off) ? ts[t - off] : 0;
        __syncthreads();
        ts[t] += x;
        __syncthreads();
    }
    if (t < B) bsum[t] = ts[t] - v;  // exclusive
}

__global__ void k_scan3(const int* __restrict__ deg, const int* __restrict__ boff,
                        int* __restrict__ rs, float* __restrict__ dinv, int N) {
    __shared__ int ts[256];
    int t = threadIdx.x;
    int base = blockIdx.x * 1024 + t * 4;
    int v[4];
    int s = 0;
#pragma unroll
    for (int j = 0; j < 4; j++) {
        v[j] = (base + j < N) ? deg[base + j] : 0;
        s += v[j];
    }
    ts[t] = s;
    __syncthreads();
    for (int off = 1; off < 256; off <<= 1) {
        int x = (t >= off) ? ts[t - off] : 0;
        __syncthreads();
        ts[t] += x;
        __syncthreads();
    }
    int run = boff[blockIdx.x] + ts[t] - s;  // exclusive
#pragma unroll
    for (int j = 0; j < 4; j++) {
        if (base + j < N) {
            rs[base + j] = run;
            dinv[base + j] = rsqrtf((float)(v[j] + 1));  // +1 self loop
            run += v[j];
        }
    }
}

// fill from partition-grouped edges: rs monotone -> col scatter window
// ~512 KB, cursor window 32 KB; stores coalesce in L2 before writeback.
__global__ void k_fillb(const int2* __restrict__ binned, const int* __restrict__ rs,
                        int* __restrict__ cursor, int* __restrict__ col, int E) {
    int e = blockIdx.x * blockDim.x + threadIdx.x;
    if (e < E) {
        int2 v = binned[e];
        int pos = rs[v.y] + atomicAdd(&cursor[v.y], 1);
        col[pos] = v.x;
    }
}

// ---- dense GEMM: out[N,64] = A[N,K] @ W[K,64] ---------------------------

template <int K>
__global__ __launch_bounds__(256) void k_gemm(const float* __restrict__ A,
                                              const float* __restrict__ W,
                                              float* __restrict__ out, int N) {
    __shared__ float Ws[64 * HID];
    __shared__ float As[64][68];
    const int tx = threadIdx.x & 15;
    const int ty = threadIdx.x >> 4;
    const int row0 = blockIdx.x * 64;

    float acc[4][4] = {};

    for (int k0 = 0; k0 < K; k0 += 64) {
        if (k0 > 0) __syncthreads();
        for (int i = threadIdx.x; i < 64 * 16; i += 256)
            ((float4*)Ws)[i] = ((const float4*)(W + (size_t)k0 * HID))[i];
        for (int i = threadIdx.x; i < 64 * 16; i += 256) {
            int r = i >> 4, c = i & 15;
            int row = row0 + r;
            float4 v = {0.f, 0.f, 0.f, 0.f};
            if (row < N) v = *(const float4*)(A + (size_t)row * K + k0 + 4 * c);
            *(float4*)&As[r][4 * c] = v;
        }
        __syncthreads();
#pragma unroll 4
        for (int k = 0; k < 64; k++) {
            float4 w = *(const float4*)&Ws[k * HID + 4 * tx];
#pragma unroll
            for (int i = 0; i < 4; i++) {
                float a = As[4 * ty + i][k];
                acc[i][0] = fmaf(a, w.x, acc[i][0]);
                acc[i][1] = fmaf(a, w.y, acc[i][1]);
                acc[i][2] = fmaf(a, w.z, acc[i][2]);
                acc[i][3] = fmaf(a, w.w, acc[i][3]);
            }
        }
    }
#pragma unroll
    for (int i = 0; i < 4; i++) {
        int row = row0 + 4 * ty + i;
        if (row < N) {
            float4 v = {acc[i][0], acc[i][1], acc[i][2], acc[i][3]};
            *(float4*)&out[(size_t)row * HID + 4 * tx] = v;
        }
    }
}

// ---- aggregation --------------------------------------------------------

__global__ void k_agg(const float* __restrict__ tin, float* __restrict__ out,
                      const int* __restrict__ rs, const int* __restrict__ deg,
                      const int* __restrict__ col,
                      const float* __restrict__ dinv, const float* __restrict__ bias,
                      int N, int relu) {
    int node = (blockIdx.x * blockDim.x + threadIdx.x) >> 4;
    int l = threadIdx.x & 15;
    if (node >= N) return;
    float di = dinv[node];
    float4 t = ((const float4*)(tin + (size_t)node * HID))[l];
    float s2 = di * di;
    float ax = s2 * t.x, ay = s2 * t.y, az = s2 * t.z, aw = s2 * t.w;

    int beg = rs[node];
    int cnt = deg[node];
    int e = 0;
    for (; e + 4 <= cnt; e += 4) {
        int s0 = col[beg + e], s1 = col[beg + e + 1];
        int sA = col[beg + e + 2], sB = col[beg + e + 3];
        float w0 = dinv[s0] * di, w1 = dinv[s1] * di;
        float w2 = dinv[sA] * di, w3 = dinv[sB] * di;
        float4 v0 = ((const float4*)(tin + (size_t)s0 * HID))[l];
        float4 v1 = ((const float4*)(tin + (size_t)s1 * HID))[l];
        float4 v2 = ((const float4*)(tin + (size_t)sA * HID))[l];
        float4 v3 = ((const float4*)(tin + (size_t)sB * HID))[l];
        ax = fmaf(w0, v0.x, ax); ay = fmaf(w0, v0.y, ay); az = fmaf(w0, v0.z, az); aw = fmaf(w0, v0.w, aw);
        ax = fmaf(w1, v1.x, ax); ay = fmaf(w1, v1.y, ay); az = fmaf(w1, v1.z, az); aw = fmaf(w1, v1.w, aw);
        ax = fmaf(w2, v2.x, ax); ay = fmaf(w2, v2.y, ay); az = fmaf(w2, v2.z, az); aw = fmaf(w2, v2.w, aw);
        ax = fmaf(w3, v3.x, ax); ay = fmaf(w3, v3.y, ay); az = fmaf(w3, v3.z, az); aw = fmaf(w3, v3.w, aw);
    }
    for (; e < cnt; e++) {
        int s = col[beg + e];
        float w = dinv[s] * di;
        float4 v = ((const float4*)(tin + (size_t)s * HID))[l];
        ax = fmaf(w, v.x, ax); ay = fmaf(w, v.y, ay); az = fmaf(w, v.z, az); aw = fmaf(w, v.w, aw);
    }
    float4 b = ((const float4*)bias)[l];
    ax += b.x; ay += b.y; az += b.z; aw += b.w;
    if (relu) {
        ax = fmaxf(ax, 0.f); ay = fmaxf(ay, 0.f);
        az = fmaxf(az, 0.f); aw = fmaxf(aw, 0.f);
    }
    float4 o = {ax, ay, az, aw};
    ((float4*)(out + (size_t)node * HID))[l] = o;
}

// ---- fused mean-pool + centroid-distance head ---------------------------

__global__ void k_pool_head(const float* __restrict__ h, const int* __restrict__ batch,
                            const float* __restrict__ cent, const float* __restrict__ rbias,
                            float* __restrict__ out, int N) {
    int g = blockIdx.x;
    int lo = 0, hi = N;
    while (lo < hi) { int mid = (lo + hi) >> 1; if (batch[mid] < g) lo = mid + 1; else hi = mid; }
    int s = lo;
    lo = 0; hi = N;
    while (lo < hi) { int mid = (lo + hi) >> 1; if (batch[mid] < g + 1) lo = mid + 1; else hi = mid; }
    int e = lo;

    __shared__ float part[4][HID];
    __shared__ float embS[HID];
    __shared__ float dS[NCENTS];
    __shared__ float dpcS[NCLS];

    int lane = threadIdx.x & 63, wid = threadIdx.x >> 6;
    float acc = 0.0f;
    for (int i = s + wid; i < e; i += 4) acc += h[(size_t)i * HID + lane];
    part[wid][lane] = acc;
    __syncthreads();
    if (wid == 0) {
        float v = part[0][lane] + part[1][lane] + part[2][lane] + part[3][lane];
        embS[lane] = v / fmaxf((float)(e - s), 1.0f);
    }
    __syncthreads();
    if (threadIdx.x < NCENTS) {
        const float* c = cent + threadIdx.x * HID;
        float d = 0.0f;
        for (int k = 0; k < HID; k++) { float df = embS[k] - c[k]; d = fmaf(df, df, d); }
        dS[threadIdx.x] = d;
    }
    __syncthreads();
    if (threadIdx.x < NCLS) {
        float m = fminf(dS[threadIdx.x * 3],
                        fminf(dS[threadIdx.x * 3 + 1], dS[threadIdx.x * 3 + 2]));
        dpcS[threadIdx.x] = m;
        out[g * (NCLS + 1) + threadIdx.x] = -m;
    }
    __syncthreads();
    if (threadIdx.x == 0) {
        float m = dpcS[0];
        for (int i = 1; i < NCLS; i++) m = fminf(m, dpcS[i]);
        out[g * (NCLS + 1) + NCLS] = m - rbias[0];
    }
}

// ---- launch -------------------------------------------------------------

extern "C" void kernel_launch(void* const* d_in, const int* in_sizes, int n_in,
                              void* d_out, int out_size, void* d_ws, size_t ws_size,
                              hipStream_t stream) {
    const float* x    = (const float*)d_in[0];
    const int*   ei   = (const int*)d_in[1];   // [2, E]: row0 = src, row1 = dst
    const int*   bat  = (const int*)d_in[2];
    const float* W1   = (const float*)d_in[3];
    const float* b1   = (const float*)d_in[4];
    const float* W2   = (const float*)d_in[5];
    const float* b2   = (const float*)d_in[6];
    const float* W3   = (const float*)d_in[7];
    const float* b3   = (const float*)d_in[8];
    const float* cent = (const float*)d_in[9];
    const float* rb   = (const float*)d_in[10];
    float* out = (float*)d_out;

    const int N = in_sizes[0] / 128;
    const int E = in_sizes[1] / 2;
    const int B1 = ceil_div(N, 1024);

    char* p = (char*)d_ws;
    float* A      = (float*)p; p += (size_t)N * HID * 4;
    float* Bb     = (float*)p; p += (size_t)N * HID * 4;
    int2*  binned = (int2*)p;  p += (size_t)E * 8;
    int*   col    = (int*)p;   p += (size_t)E * 4;
    float* dinv   = (float*)p; p += (size_t)N * 4;
    int*   rs     = (int*)p;   p += (size_t)N * 4;
    int*   bsum   = (int*)p;   p += (size_t)((B1 + 1) & ~1) * 4;
    int*   binBase= (int*)p;   p += NBIN * 4;
    // zeroed region: deg[N] | cursor[N] | binCnt[NBIN] | binCur[NBIN]
    int*   deg    = (int*)p;   p += (size_t)N * 4;
    int*   cur    = (int*)p;   p += (size_t)N * 4;
    int*   binCnt = (int*)p;   p += NBIN * 4;
    int*   binCur = (int*)p;   p += NBIN * 4;

    hipMemsetAsync(deg, 0, ((size_t)2 * N + 2 * NBIN) * 4, stream);

    k_count<<<ceil_div(E, 2048), 256, 0, stream>>>(ei + E, binCnt, E);
    k_binoff<<<1, 64, 0, stream>>>(binCnt, binBase);
    k_bin<<<ceil_div(E, CHUNK), 256, 0, stream>>>(ei, ei + E, binBase, binCur, binned, E);
    k_degb<<<ceil_div(E, 256), 256, 0, stream>>>(binned, deg, E);
    k_scan1<<<B1, 256, 0, stream>>>(deg, bsum, N);
    k_scan2<<<1, 256, 0, stream>>>(bsum, B1);
    k_scan3<<<B1, 256, 0, stream>>>(deg, bsum, rs, dinv, N);
    k_fillb<<<ceil_div(E, 256), 256, 0, stream>>>(binned, rs, cur, col, E);

    k_gemm<128><<<ceil_div(N, 64), 256, 0, stream>>>(x, W1, A, N);
    k_agg<<<ceil_div(N * 16, 256), 256, 0, stream>>>(A, Bb, rs, deg, col, dinv, b1, N, 1);
    k_gemm<64><<<ceil_div(N, 64), 256, 0, stream>>>(Bb, W2, A, N);
    k_agg<<<ceil_div(N * 16, 256), 256, 0, stream>>>(A, Bb, rs, deg, col, dinv, b2, N, 1);
    k_gemm<64><<<ceil_div(N, 64), 256, 0, stream>>>(Bb, W3, A, N);
    k_agg<<<ceil_div(N * 16, 256), 256, 0, stream>>>(A, Bb, rs, deg, col, dinv, b3, N, 0);

    k_pool_head<<<1024, 256, 0, stream>>>(Bb, bat, cent, rb, out, N);
}

// Round 6
// 437.763 us; speedup vs baseline: 1.2459x; 1.2459x over previous
//
#include <hip/hip_runtime.h>

#define HID 64
#define NCLS 16
#define NCENT 3
#define NCENTS (NCLS * NCENT)
#define BSHIFT 9               // 512 nodes per bin
#define BINW (1 << BSHIFT)
#define NBINMAX 256            // supports N <= 131072
#define CHUNK 4096             // edges per k_bin/k_count block
#define EPT (CHUNK / 256)

static inline int ceil_div(int a, int b) { return (a + b - 1) / b; }

// ---- edge binning (counting-sort by dst>>BSHIFT) ------------------------

__global__ void k_count(const int* __restrict__ dst, int* __restrict__ binCnt,
                        int E, int nbins) {
    __shared__ int c[NBINMAX];
    for (int i = threadIdx.x; i < nbins; i += 256) c[i] = 0;
    __syncthreads();
    int e = blockIdx.x * CHUNK + threadIdx.x;
#pragma unroll
    for (int j = 0; j < EPT; j++, e += 256)
        if (e < E) atomicAdd(&c[dst[e] >> BSHIFT], 1);
    __syncthreads();
    for (int i = threadIdx.x; i < nbins; i += 256)
        if (c[i] > 0) atomicAdd(&binCnt[i], c[i]);
}

__global__ void k_binoff(const int* __restrict__ binCnt, int* __restrict__ binBase,
                         int nbins, int E) {
    __shared__ int ts[NBINMAX];
    int t = threadIdx.x;
    int v = (t < nbins) ? binCnt[t] : 0;
    ts[t] = v;
    __syncthreads();
    for (int off = 1; off < NBINMAX; off <<= 1) {
        int x = (t >= off) ? ts[t - off] : 0;
        __syncthreads();
        ts[t] += x;
        __syncthreads();
    }
    if (t < nbins) binBase[t] = ts[t] - v;   // exclusive
    if (t == 0) binBase[nbins] = E;
}

// Stage CHUNK edges in LDS packed by bin; copy out contiguous per-bin segments.
__global__ __launch_bounds__(256) void k_bin(const int* __restrict__ src,
                                             const int* __restrict__ dst,
                                             const int* __restrict__ binBase,
                                             int* __restrict__ binCur,
                                             int2* __restrict__ binned,
                                             int E, int nbins) {
    __shared__ int cnt[NBINMAX], off[NBINMAX], gbase[NBINMAX];
    __shared__ int2 stage[CHUNK];
    const int c0 = blockIdx.x * CHUNK;
    const int tid = threadIdx.x;
    cnt[tid] = 0;
    __syncthreads();
    int sv[EPT], dv[EPT];
#pragma unroll
    for (int j = 0; j < EPT; j++) {
        int e = c0 + j * 256 + tid;
        dv[j] = -1;
        if (e < E) {
            sv[j] = src[e];
            dv[j] = dst[e];
            atomicAdd(&cnt[dv[j] >> BSHIFT], 1);
        }
    }
    __syncthreads();
    off[tid] = cnt[tid];
    __syncthreads();
    for (int o = 1; o < NBINMAX; o <<= 1) {
        int x = (tid >= o) ? off[tid - o] : 0;
        __syncthreads();
        off[tid] += x;
        __syncthreads();
    }
    int excl = off[tid] - cnt[tid];
    __syncthreads();
    off[tid] = excl;
    gbase[tid] = (tid < nbins && cnt[tid] > 0) ? atomicAdd(&binCur[tid], cnt[tid]) : 0;
    cnt[tid] = 0;  // reuse as local cursor
    __syncthreads();
#pragma unroll
    for (int j = 0; j < EPT; j++)
        if (dv[j] >= 0) {
            int b = dv[j] >> BSHIFT;
            int pos = off[b] + atomicAdd(&cnt[b], 1);
            stage[pos] = make_int2(sv[j], dv[j]);
        }
    __syncthreads();
    int tot = min(CHUNK, E - c0);
    for (int i = tid; i < tot; i += 256) {
        int2 v = stage[i];
        int b = v.y >> BSHIFT;
        binned[binBase[b] + gbase[b] + (i - off[b])] = v;
    }
}

// One block per bin: LDS histogram of its contiguous segment -> deg (no atomics).
__global__ __launch_bounds__(256) void k_hist(const int2* __restrict__ binned,
                                              const int* __restrict__ binBase,
                                              int* __restrict__ deg, int N) {
    __shared__ int c[BINW];
    int b = blockIdx.x;
    int s = binBase[b], e = binBase[b + 1];
    int n0 = b << BSHIFT;
    for (int i = threadIdx.x; i < BINW; i += 256) c[i] = 0;
    __syncthreads();
    for (int i = s + threadIdx.x; i < e; i += 256)
        atomicAdd(&c[binned[i].y - n0], 1);
    __syncthreads();
    for (int i = threadIdx.x; i < BINW; i += 256)
        if (n0 + i < N) deg[n0 + i] = c[i];
}

// ---- exclusive scan of deg -> rs (node-ordered), plus dinv --------------

__global__ void k_scan1(const int* __restrict__ deg, int* __restrict__ bsum, int N) {
    __shared__ int ts[256];
    int t = threadIdx.x;
    int base = blockIdx.x * 1024 + t * 4;
    int s = 0;
#pragma unroll
    for (int j = 0; j < 4; j++) if (base + j < N) s += deg[base + j];
    ts[t] = s;
    __syncthreads();
    for (int off = 128; off > 0; off >>= 1) {
        if (t < off) ts[t] += ts[t + off];
        __syncthreads();
    }
    if (t == 0) bsum[blockIdx.x] = ts[0];
}

__global__ void k_scan2(int* __restrict__ bsum, int B) {
    __shared__ int ts[256];
    int t = threadIdx.x;
    int v = (t < B) ? bsum[t] : 0;
    ts[t] = v;
    __syncthreads();
    for (int off = 1; off < 256; off <<= 1) {
        int x = (t >= off) ? ts[t - off] : 0;
        __syncthreads();
        ts[t] += x;
        __syncthreads();
    }
    if (t < B) bsum[t] = ts[t] - v;  // exclusive
}

__global__ void k_scan3(const int* __restrict__ deg, const int* __restrict__ boff,
                        int* __restrict__ rs, float* __restrict__ dinv, int N) {
    __shared__ int ts[256];
    int t = threadIdx.x;
    int base = blockIdx.x * 1024 + t * 4;
    int v[4];
    int s = 0;
#pragma unroll
    for (int j = 0; j < 4; j++) {
        v[j] = (base + j < N) ? deg[base + j] : 0;
        s += v[j];
    }
    ts[t] = s;
    __syncthreads();
    for (int off = 1; off < 256; off <<= 1) {
        int x = (t >= off) ? ts[t - off] : 0;
        __syncthreads();
        ts[t] += x;
        __syncthreads();
    }
    int run = boff[blockIdx.x] + ts[t] - s;  // exclusive
#pragma unroll
    for (int j = 0; j < 4; j++) {
        if (base + j < N) {
            rs[base + j] = run;
            dinv[base + j] = rsqrtf((float)(v[j] + 1));  // +1 self loop
            run += v[j];
        }
    }
}

// One block per bin: scatter col within the bin's private ~25 KB window.
// Single CU -> single XCD L2 -> each line written back once.
__global__ __launch_bounds__(256) void k_fillc(const int2* __restrict__ binned,
                                               const int* __restrict__ binBase,
                                               const int* __restrict__ rs,
                                               int* __restrict__ col, int N) {
    __shared__ int cur[BINW];
    __shared__ int rsl[BINW];
    int b = blockIdx.x;
    int s = binBase[b], e = binBase[b + 1];
    int n0 = b << BSHIFT;
    for (int i = threadIdx.x; i < BINW; i += 256) {
        cur[i] = 0;
        rsl[i] = (n0 + i < N) ? rs[n0 + i] : 0;
    }
    __syncthreads();
    for (int i = s + threadIdx.x; i < e; i += 256) {
        int2 v = binned[i];
        int lo = v.y - n0;
        int pos = rsl[lo] + atomicAdd(&cur[lo], 1);
        col[pos] = v.x;
    }
}

// ---- dense GEMM: out[N,64] = A[N,K] @ W[K,64] ---------------------------

template <int K>
__global__ __launch_bounds__(256) void k_gemm(const float* __restrict__ A,
                                              const float* __restrict__ W,
                                              float* __restrict__ out, int N) {
    __shared__ float Ws[64 * HID];
    __shared__ float As[64][68];
    const int tx = threadIdx.x & 15;
    const int ty = threadIdx.x >> 4;
    const int row0 = blockIdx.x * 64;

    float acc[4][4] = {};

    for (int k0 = 0; k0 < K; k0 += 64) {
        if (k0 > 0) __syncthreads();
        for (int i = threadIdx.x; i < 64 * 16; i += 256)
            ((float4*)Ws)[i] = ((const float4*)(W + (size_t)k0 * HID))[i];
        for (int i = threadIdx.x; i < 64 * 16; i += 256) {
            int r = i >> 4, c = i & 15;
            int row = row0 + r;
            float4 v = {0.f, 0.f, 0.f, 0.f};
            if (row < N) v = *(const float4*)(A + (size_t)row * K + k0 + 4 * c);
            *(float4*)&As[r][4 * c] = v;
        }
        __syncthreads();
#pragma unroll 4
        for (int k = 0; k < 64; k++) {
            float4 w = *(const float4*)&Ws[k * HID + 4 * tx];
#pragma unroll
            for (int i = 0; i < 4; i++) {
                float a = As[4 * ty + i][k];
                acc[i][0] = fmaf(a, w.x, acc[i][0]);
                acc[i][1] = fmaf(a, w.y, acc[i][1]);
                acc[i][2] = fmaf(a, w.z, acc[i][2]);
                acc[i][3] = fmaf(a, w.w, acc[i][3]);
            }
        }
    }
#pragma unroll
    for (int i = 0; i < 4; i++) {
        int row = row0 + 4 * ty + i;
        if (row < N) {
            float4 v = {acc[i][0], acc[i][1], acc[i][2], acc[i][3]};
            *(float4*)&out[(size_t)row * HID + 4 * tx] = v;
        }
    }
}

// ---- aggregation --------------------------------------------------------

__global__ void k_agg(const float* __restrict__ tin, float* __restrict__ out,
                      const int* __restrict__ rs, const int* __restrict__ deg,
                      const int* __restrict__ col,
                      const float* __restrict__ dinv, const float* __restrict__ bias,
                      int N, int relu) {
    int node = (blockIdx.x * blockDim.x + threadIdx.x) >> 4;
    int l = threadIdx.x & 15;
    if (node >= N) return;
    float di = dinv[node];
    float4 t = ((const float4*)(tin + (size_t)node * HID))[l];
    float s2 = di * di;
    float ax = s2 * t.x, ay = s2 * t.y, az = s2 * t.z, aw = s2 * t.w;

    int beg = rs[node];
    int cnt = deg[node];
    int e = 0;
    for (; e + 4 <= cnt; e += 4) {
        int s0 = col[beg + e], s1 = col[beg + e + 1];
        int sA = col[beg + e + 2], sB = col[beg + e + 3];
        float w0 = dinv[s0] * di, w1 = dinv[s1] * di;
        float w2 = dinv[sA] * di, w3 = dinv[sB] * di;
        float4 v0 = ((const float4*)(tin + (size_t)s0 * HID))[l];
        float4 v1 = ((const float4*)(tin + (size_t)s1 * HID))[l];
        float4 v2 = ((const float4*)(tin + (size_t)sA * HID))[l];
        float4 v3 = ((const float4*)(tin + (size_t)sB * HID))[l];
        ax = fmaf(w0, v0.x, ax); ay = fmaf(w0, v0.y, ay); az = fmaf(w0, v0.z, az); aw = fmaf(w0, v0.w, aw);
        ax = fmaf(w1, v1.x, ax); ay = fmaf(w1, v1.y, ay); az = fmaf(w1, v1.z, az); aw = fmaf(w1, v1.w, aw);
        ax = fmaf(w2, v2.x, ax); ay = fmaf(w2, v2.y, ay); az = fmaf(w2, v2.z, az); aw = fmaf(w2, v2.w, aw);
        ax = fmaf(w3, v3.x, ax); ay = fmaf(w3, v3.y, ay); az = fmaf(w3, v3.z, az); aw = fmaf(w3, v3.w, aw);
    }
    for (; e < cnt; e++) {
        int s = col[beg + e];
        float w = dinv[s] * di;
        float4 v = ((const float4*)(tin + (size_t)s * HID))[l];
        ax = fmaf(w, v.x, ax); ay = fmaf(w, v.y, ay); az = fmaf(w, v.z, az); aw = fmaf(w, v.w, aw);
    }
    float4 b = ((const float4*)bias)[l];
    ax += b.x; ay += b.y; az += b.z; aw += b.w;
    if (relu) {
        ax = fmaxf(ax, 0.f); ay = fmaxf(ay, 0.f);
        az = fmaxf(az, 0.f); aw = fmaxf(aw, 0.f);
    }
    float4 o = {ax, ay, az, aw};
    ((float4*)(out + (size_t)node * HID))[l] = o;
}

// ---- fused mean-pool + centroid-distance head ---------------------------

__global__ void k_pool_head(const float* __restrict__ h, const int* __restrict__ batch,
                            const float* __restrict__ cent, const float* __restrict__ rbias,
                            float* __restrict__ out, int N) {
    int g = blockIdx.x;
    int lo = 0, hi = N;
    while (lo < hi) { int mid = (lo + hi) >> 1; if (batch[mid] < g) lo = mid + 1; else hi = mid; }
    int s = lo;
    lo = 0; hi = N;
    while (lo < hi) { int mid = (lo + hi) >> 1; if (batch[mid] < g + 1) lo = mid + 1; else hi = mid; }
    int e = lo;

    __shared__ float part[4][HID];
    __shared__ float embS[HID];
    __shared__ float dS[NCENTS];
    __shared__ float dpcS[NCLS];

    int lane = threadIdx.x & 63, wid = threadIdx.x >> 6;
    float acc = 0.0f;
    for (int i = s + wid; i < e; i += 4) acc += h[(size_t)i * HID + lane];
    part[wid][lane] = acc;
    __syncthreads();
    if (wid == 0) {
        float v = part[0][lane] + part[1][lane] + part[2][lane] + part[3][lane];
        embS[lane] = v / fmaxf((float)(e - s), 1.0f);
    }
    __syncthreads();
    if (threadIdx.x < NCENTS) {
        const float* c = cent + threadIdx.x * HID;
        float d = 0.0f;
        for (int k = 0; k < HID; k++) { float df = embS[k] - c[k]; d = fmaf(df, df, d); }
        dS[threadIdx.x] = d;
    }
    __syncthreads();
    if (threadIdx.x < NCLS) {
        float m = fminf(dS[threadIdx.x * 3],
                        fminf(dS[threadIdx.x * 3 + 1], dS[threadIdx.x * 3 + 2]));
        dpcS[threadIdx.x] = m;
        out[g * (NCLS + 1) + threadIdx.x] = -m;
    }
    __syncthreads();
    if (threadIdx.x == 0) {
        float m = dpcS[0];
        for (int i = 1; i < NCLS; i++) m = fminf(m, dpcS[i]);
        out[g * (NCLS + 1) + NCLS] = m - rbias[0];
    }
}

// ---- launch -------------------------------------------------------------

extern "C" void kernel_launch(void* const* d_in, const int* in_sizes, int n_in,
                              void* d_out, int out_size, void* d_ws, size_t ws_size,
                              hipStream_t stream) {
    const float* x    = (const float*)d_in[0];
    const int*   ei   = (const int*)d_in[1];   // [2, E]: row0 = src, row1 = dst
    const int*   bat  = (const int*)d_in[2];
    const float* W1   = (const float*)d_in[3];
    const float* b1   = (const float*)d_in[4];
    const float* W2   = (const float*)d_in[5];
    const float* b2   = (const float*)d_in[6];
    const float* W3   = (const float*)d_in[7];
    const float* b3   = (const float*)d_in[8];
    const float* cent = (const float*)d_in[9];
    const float* rb   = (const float*)d_in[10];
    float* out = (float*)d_out;

    const int N = in_sizes[0] / 128;
    const int E = in_sizes[1] / 2;
    const int B1 = ceil_div(N, 1024);
    const int nbins = (N + BINW - 1) >> BSHIFT;

    char* p = (char*)d_ws;
    float* A      = (float*)p; p += (size_t)N * HID * 4;
    float* Bb     = (float*)p; p += (size_t)N * HID * 4;
    int2*  binned = (int2*)p;  p += (size_t)E * 8;
    int*   col    = (int*)p;   p += (size_t)E * 4;
    float* dinv   = (float*)p; p += (size_t)N * 4;
    int*   rs     = (int*)p;   p += (size_t)N * 4;
    int*   deg    = (int*)p;   p += (size_t)N * 4;
    int*   bsum   = (int*)p;   p += (size_t)((B1 + 1) & ~1) * 4;
    int*   binBase= (int*)p;   p += (NBINMAX + 2) * 4;
    // zeroed region: binCnt | binCur
    int*   binCnt = (int*)p;   p += NBINMAX * 4;
    int*   binCur = (int*)p;   p += NBINMAX * 4;

    hipMemsetAsync(binCnt, 0, 2 * NBINMAX * 4, stream);

    k_count<<<ceil_div(E, CHUNK), 256, 0, stream>>>(ei + E, binCnt, E, nbins);
    k_binoff<<<1, 256, 0, stream>>>(binCnt, binBase, nbins, E);
    k_bin<<<ceil_div(E, CHUNK), 256, 0, stream>>>(ei, ei + E, binBase, binCur, binned, E, nbins);
    k_hist<<<nbins, 256, 0, stream>>>(binned, binBase, deg, N);
    k_scan1<<<B1, 256, 0, stream>>>(deg, bsum, N);
    k_scan2<<<1, 256, 0, stream>>>(bsum, B1);
    k_scan3<<<B1, 256, 0, stream>>>(deg, bsum, rs, dinv, N);
    k_fillc<<<nbins, 256, 0, stream>>>(binned, binBase, rs, col, N);

    k_gemm<128><<<ceil_div(N, 64), 256, 0, stream>>>(x, W1, A, N);
    k_agg<<<ceil_div(N * 16, 256), 256, 0, stream>>>(A, Bb, rs, deg, col, dinv, b1, N, 1);
    k_gemm<64><<<ceil_div(N, 64), 256, 0, stream>>>(Bb, W2, A, N);
    k_agg<<<ceil_div(N * 16, 256), 256, 0, stream>>>(A, Bb, rs, deg, col, dinv, b2, N, 1);
    k_gemm<64><<<ceil_div(N, 64), 256, 0, stream>>>(Bb, W3, A, N);
    k_agg<<<ceil_div(N * 16, 256), 256, 0, stream>>>(A, Bb, rs, deg, col, dinv, b3, N, 0);

    k_pool_head<<<1024, 256, 0, stream>>>(Bb, bat, cent, rb, out, N);
}

// Round 7
// 371.177 us; speedup vs baseline: 1.4694x; 1.1794x over previous
//
#include <hip/hip_runtime.h>

#define HID 64
#define NCLS 16
#define NCENT 3
#define NCENTS (NCLS * NCENT)
#define BSHIFT 9               // 512 nodes per bin
#define BINW (1 << BSHIFT)
#define NBINMAX 256            // supports N <= 131072
#define CHUNK 4096             // edges per k_bin/k_count block
#define EPT (CHUNK / 256)

static inline int ceil_div(int a, int b) { return (a + b - 1) / b; }

__device__ inline unsigned short f2bf(float f) {   // round-to-nearest-even
    unsigned int u = __float_as_uint(f);
    return (unsigned short)((u + 0x7FFFu + ((u >> 16) & 1u)) >> 16);
}
__device__ inline float bf2f(unsigned short h) {
    return __uint_as_float(((unsigned int)h) << 16);
}

// ---- edge binning (counting-sort by dst>>BSHIFT) ------------------------

__global__ void k_count(const int* __restrict__ dst, int* __restrict__ binCnt,
                        int E, int nbins) {
    __shared__ int c[NBINMAX];
    for (int i = threadIdx.x; i < nbins; i += 256) c[i] = 0;
    __syncthreads();
    int e = blockIdx.x * CHUNK + threadIdx.x;
#pragma unroll
    for (int j = 0; j < EPT; j++, e += 256)
        if (e < E) atomicAdd(&c[dst[e] >> BSHIFT], 1);
    __syncthreads();
    for (int i = threadIdx.x; i < nbins; i += 256)
        if (c[i] > 0) atomicAdd(&binCnt[i], c[i]);
}

__global__ void k_binoff(const int* __restrict__ binCnt, int* __restrict__ binBase,
                         int nbins, int E) {
    __shared__ int ts[NBINMAX];
    int t = threadIdx.x;
    int v = (t < nbins) ? binCnt[t] : 0;
    ts[t] = v;
    __syncthreads();
    for (int off = 1; off < NBINMAX; off <<= 1) {
        int x = (t >= off) ? ts[t - off] : 0;
        __syncthreads();
        ts[t] += x;
        __syncthreads();
    }
    if (t < nbins) binBase[t] = ts[t] - v;   // exclusive
    if (t == 0) binBase[nbins] = E;
}

// Stage CHUNK edges in LDS packed by bin; copy out contiguous per-bin segments.
__global__ __launch_bounds__(256) void k_bin(const int* __restrict__ src,
                                             const int* __restrict__ dst,
                                             const int* __restrict__ binBase,
                                             int* __restrict__ binCur,
                                             int2* __restrict__ binned,
                                             int E, int nbins) {
    __shared__ int cnt[NBINMAX], off[NBINMAX], gbase[NBINMAX];
    __shared__ int2 stage[CHUNK];
    const int c0 = blockIdx.x * CHUNK;
    const int tid = threadIdx.x;
    cnt[tid] = 0;
    __syncthreads();
    int sv[EPT], dv[EPT];
#pragma unroll
    for (int j = 0; j < EPT; j++) {
        int e = c0 + j * 256 + tid;
        dv[j] = -1;
        if (e < E) {
            sv[j] = src[e];
            dv[j] = dst[e];
            atomicAdd(&cnt[dv[j] >> BSHIFT], 1);
        }
    }
    __syncthreads();
    off[tid] = cnt[tid];
    __syncthreads();
    for (int o = 1; o < NBINMAX; o <<= 1) {
        int x = (tid >= o) ? off[tid - o] : 0;
        __syncthreads();
        off[tid] += x;
        __syncthreads();
    }
    int excl = off[tid] - cnt[tid];
    __syncthreads();
    off[tid] = excl;
    gbase[tid] = (tid < nbins && cnt[tid] > 0) ? atomicAdd(&binCur[tid], cnt[tid]) : 0;
    cnt[tid] = 0;  // reuse as local cursor
    __syncthreads();
#pragma unroll
    for (int j = 0; j < EPT; j++)
        if (dv[j] >= 0) {
            int b = dv[j] >> BSHIFT;
            int pos = off[b] + atomicAdd(&cnt[b], 1);
            stage[pos] = make_int2(sv[j], dv[j]);
        }
    __syncthreads();
    int tot = min(CHUNK, E - c0);
    for (int i = tid; i < tot; i += 256) {
        int2 v = stage[i];
        int b = v.y >> BSHIFT;
        binned[binBase[b] + gbase[b] + (i - off[b])] = v;
    }
}

// One block per bin: LDS histogram of its contiguous segment -> deg (no atomics).
__global__ __launch_bounds__(256) void k_hist(const int2* __restrict__ binned,
                                              const int* __restrict__ binBase,
                                              int* __restrict__ deg, int N) {
    __shared__ int c[BINW];
    int b = blockIdx.x;
    int s = binBase[b], e = binBase[b + 1];
    int n0 = b << BSHIFT;
    for (int i = threadIdx.x; i < BINW; i += 256) c[i] = 0;
    __syncthreads();
    for (int i = s + threadIdx.x; i < e; i += 256)
        atomicAdd(&c[binned[i].y - n0], 1);
    __syncthreads();
    for (int i = threadIdx.x; i < BINW; i += 256)
        if (n0 + i < N) deg[n0 + i] = c[i];
}

// ---- exclusive scan of deg -> rs (node-ordered), plus dinv --------------

__global__ void k_scan1(const int* __restrict__ deg, int* __restrict__ bsum, int N) {
    __shared__ int ts[256];
    int t = threadIdx.x;
    int base = blockIdx.x * 1024 + t * 4;
    int s = 0;
#pragma unroll
    for (int j = 0; j < 4; j++) if (base + j < N) s += deg[base + j];
    ts[t] = s;
    __syncthreads();
    for (int off = 128; off > 0; off >>= 1) {
        if (t < off) ts[t] += ts[t + off];
        __syncthreads();
    }
    if (t == 0) bsum[blockIdx.x] = ts[0];
}

__global__ void k_scan2(int* __restrict__ bsum, int B) {
    __shared__ int ts[256];
    int t = threadIdx.x;
    int v = (t < B) ? bsum[t] : 0;
    ts[t] = v;
    __syncthreads();
    for (int off = 1; off < 256; off <<= 1) {
        int x = (t >= off) ? ts[t - off] : 0;
        __syncthreads();
        ts[t] += x;
        __syncthreads();
    }
    if (t < B) bsum[t] = ts[t] - v;  // exclusive
}

__global__ void k_scan3(const int* __restrict__ deg, const int* __restrict__ boff,
                        int* __restrict__ rs, float* __restrict__ dinv, int N) {
    __shared__ int ts[256];
    int t = threadIdx.x;
    int base = blockIdx.x * 1024 + t * 4;
    int v[4];
    int s = 0;
#pragma unroll
    for (int j = 0; j < 4; j++) {
        v[j] = (base + j < N) ? deg[base + j] : 0;
        s += v[j];
    }
    ts[t] = s;
    __syncthreads();
    for (int off = 1; off < 256; off <<= 1) {
        int x = (t >= off) ? ts[t - off] : 0;
        __syncthreads();
        ts[t] += x;
        __syncthreads();
    }
    int run = boff[blockIdx.x] + ts[t] - s;  // exclusive
#pragma unroll
    for (int j = 0; j < 4; j++) {
        if (base + j < N) {
            rs[base + j] = run;
            dinv[base + j] = rsqrtf((float)(v[j] + 1));  // +1 self loop
            run += v[j];
        }
    }
}

// One block per bin: scatter col within the bin's private ~25 KB window.
__global__ __launch_bounds__(256) void k_fillc(const int2* __restrict__ binned,
                                               const int* __restrict__ binBase,
                                               const int* __restrict__ rs,
                                               int* __restrict__ col, int N) {
    __shared__ int cur[BINW];
    __shared__ int rsl[BINW];
    int b = blockIdx.x;
    int s = binBase[b], e = binBase[b + 1];
    int n0 = b << BSHIFT;
    for (int i = threadIdx.x; i < BINW; i += 256) {
        cur[i] = 0;
        rsl[i] = (n0 + i < N) ? rs[n0 + i] : 0;
    }
    __syncthreads();
    for (int i = s + threadIdx.x; i < e; i += 256) {
        int2 v = binned[i];
        int lo = v.y - n0;
        int pos = rsl[lo] + atomicAdd(&cur[lo], 1);
        col[pos] = v.x;
    }
}

// ---- dense GEMM: out[N,64] = A[N,K] @ W[K,64], output rounded to bf16 ----
// bf16 output feeds ONLY the gather kernels (k_agg); fp32 math elsewhere.

template <int K>
__global__ __launch_bounds__(256) void k_gemm(const float* __restrict__ A,
                                              const float* __restrict__ W,
                                              unsigned short* __restrict__ out, int N) {
    __shared__ float Ws[64 * HID];
    __shared__ float As[64][68];
    const int tx = threadIdx.x & 15;
    const int ty = threadIdx.x >> 4;
    const int row0 = blockIdx.x * 64;

    float acc[4][4] = {};

    for (int k0 = 0; k0 < K; k0 += 64) {
        if (k0 > 0) __syncthreads();
        for (int i = threadIdx.x; i < 64 * 16; i += 256)
            ((float4*)Ws)[i] = ((const float4*)(W + (size_t)k0 * HID))[i];
        for (int i = threadIdx.x; i < 64 * 16; i += 256) {
            int r = i >> 4, c = i & 15;
            int row = row0 + r;
            float4 v = {0.f, 0.f, 0.f, 0.f};
            if (row < N) v = *(const float4*)(A + (size_t)row * K + k0 + 4 * c);
            *(float4*)&As[r][4 * c] = v;
        }
        __syncthreads();
#pragma unroll 4
        for (int k = 0; k < 64; k++) {
            float4 w = *(const float4*)&Ws[k * HID + 4 * tx];
#pragma unroll
            for (int i = 0; i < 4; i++) {
                float a = As[4 * ty + i][k];
                acc[i][0] = fmaf(a, w.x, acc[i][0]);
                acc[i][1] = fmaf(a, w.y, acc[i][1]);
                acc[i][2] = fmaf(a, w.z, acc[i][2]);
                acc[i][3] = fmaf(a, w.w, acc[i][3]);
            }
        }
    }
#pragma unroll
    for (int i = 0; i < 4; i++) {
        int row = row0 + 4 * ty + i;
        if (row < N) {
            ushort4 v = {f2bf(acc[i][0]), f2bf(acc[i][1]), f2bf(acc[i][2]), f2bf(acc[i][3])};
            *(ushort4*)&out[(size_t)row * HID + 4 * tx] = v;
        }
    }
}

// ---- aggregation: gathers 128B bf16 rows; accumulates fp32 --------------

__global__ void k_agg(const unsigned short* __restrict__ tin, float* __restrict__ out,
                      const int* __restrict__ rs, const int* __restrict__ deg,
                      const int* __restrict__ col,
                      const float* __restrict__ dinv, const float* __restrict__ bias,
                      int N, int relu) {
    int node = (blockIdx.x * blockDim.x + threadIdx.x) >> 4;
    int l = threadIdx.x & 15;
    if (node >= N) return;
    float di = dinv[node];
    ushort4 tb = ((const ushort4*)(tin + (size_t)node * HID))[l];
    float s2 = di * di;
    float ax = s2 * bf2f(tb.x), ay = s2 * bf2f(tb.y);
    float az = s2 * bf2f(tb.z), aw = s2 * bf2f(tb.w);

    int beg = rs[node];
    int cnt = deg[node];
    int e = 0;
    for (; e + 4 <= cnt; e += 4) {
        int s0 = col[beg + e], s1 = col[beg + e + 1];
        int sA = col[beg + e + 2], sB = col[beg + e + 3];
        float w0 = dinv[s0] * di, w1 = dinv[s1] * di;
        float w2 = dinv[sA] * di, w3 = dinv[sB] * di;
        ushort4 v0 = ((const ushort4*)(tin + (size_t)s0 * HID))[l];
        ushort4 v1 = ((const ushort4*)(tin + (size_t)s1 * HID))[l];
        ushort4 v2 = ((const ushort4*)(tin + (size_t)sA * HID))[l];
        ushort4 v3 = ((const ushort4*)(tin + (size_t)sB * HID))[l];
        ax = fmaf(w0, bf2f(v0.x), ax); ay = fmaf(w0, bf2f(v0.y), ay);
        az = fmaf(w0, bf2f(v0.z), az); aw = fmaf(w0, bf2f(v0.w), aw);
        ax = fmaf(w1, bf2f(v1.x), ax); ay = fmaf(w1, bf2f(v1.y), ay);
        az = fmaf(w1, bf2f(v1.z), az); aw = fmaf(w1, bf2f(v1.w), aw);
        ax = fmaf(w2, bf2f(v2.x), ax); ay = fmaf(w2, bf2f(v2.y), ay);
        az = fmaf(w2, bf2f(v2.z), az); aw = fmaf(w2, bf2f(v2.w), aw);
        ax = fmaf(w3, bf2f(v3.x), ax); ay = fmaf(w3, bf2f(v3.y), ay);
        az = fmaf(w3, bf2f(v3.z), az); aw = fmaf(w3, bf2f(v3.w), aw);
    }
    for (; e < cnt; e++) {
        int s = col[beg + e];
        float w = dinv[s] * di;
        ushort4 v = ((const ushort4*)(tin + (size_t)s * HID))[l];
        ax = fmaf(w, bf2f(v.x), ax); ay = fmaf(w, bf2f(v.y), ay);
        az = fmaf(w, bf2f(v.z), az); aw = fmaf(w, bf2f(v.w), aw);
    }
    float4 b = ((const float4*)bias)[l];
    ax += b.x; ay += b.y; az += b.z; aw += b.w;
    if (relu) {
        ax = fmaxf(ax, 0.f); ay = fmaxf(ay, 0.f);
        az = fmaxf(az, 0.f); aw = fmaxf(aw, 0.f);
    }
    float4 o = {ax, ay, az, aw};
    ((float4*)(out + (size_t)node * HID))[l] = o;
}

// ---- fused mean-pool + centroid-distance head ---------------------------

__global__ void k_pool_head(const float* __restrict__ h, const int* __restrict__ batch,
                            const float* __restrict__ cent, const float* __restrict__ rbias,
                            float* __restrict__ out, int N) {
    int g = blockIdx.x;
    int lo = 0, hi = N;
    while (lo < hi) { int mid = (lo + hi) >> 1; if (batch[mid] < g) lo = mid + 1; else hi = mid; }
    int s = lo;
    lo = 0; hi = N;
    while (lo < hi) { int mid = (lo + hi) >> 1; if (batch[mid] < g + 1) lo = mid + 1; else hi = mid; }
    int e = lo;

    __shared__ float part[4][HID];
    __shared__ float embS[HID];
    __shared__ float dS[NCENTS];
    __shared__ float dpcS[NCLS];

    int lane = threadIdx.x & 63, wid = threadIdx.x >> 6;
    float acc = 0.0f;
    for (int i = s + wid; i < e; i += 4) acc += h[(size_t)i * HID + lane];
    part[wid][lane] = acc;
    __syncthreads();
    if (wid == 0) {
        float v = part[0][lane] + part[1][lane] + part[2][lane] + part[3][lane];
        embS[lane] = v / fmaxf((float)(e - s), 1.0f);
    }
    __syncthreads();
    if (threadIdx.x < NCENTS) {
        const float* c = cent + threadIdx.x * HID;
        float d = 0.0f;
        for (int k = 0; k < HID; k++) { float df = embS[k] - c[k]; d = fmaf(df, df, d); }
        dS[threadIdx.x] = d;
    }
    __syncthreads();
    if (threadIdx.x < NCLS) {
        float m = fminf(dS[threadIdx.x * 3],
                        fminf(dS[threadIdx.x * 3 + 1], dS[threadIdx.x * 3 + 2]));
        dpcS[threadIdx.x] = m;
        out[g * (NCLS + 1) + threadIdx.x] = -m;
    }
    __syncthreads();
    if (threadIdx.x == 0) {
        float m = dpcS[0];
        for (int i = 1; i < NCLS; i++) m = fminf(m, dpcS[i]);
        out[g * (NCLS + 1) + NCLS] = m - rbias[0];
    }
}

// ---- launch -------------------------------------------------------------

extern "C" void kernel_launch(void* const* d_in, const int* in_sizes, int n_in,
                              void* d_out, int out_size, void* d_ws, size_t ws_size,
                              hipStream_t stream) {
    const float* x    = (const float*)d_in[0];
    const int*   ei   = (const int*)d_in[1];   // [2, E]: row0 = src, row1 = dst
    const int*   bat  = (const int*)d_in[2];
    const float* W1   = (const float*)d_in[3];
    const float* b1   = (const float*)d_in[4];
    const float* W2   = (const float*)d_in[5];
    const float* b2   = (const float*)d_in[6];
    const float* W3   = (const float*)d_in[7];
    const float* b3   = (const float*)d_in[8];
    const float* cent = (const float*)d_in[9];
    const float* rb   = (const float*)d_in[10];
    float* out = (float*)d_out;

    const int N = in_sizes[0] / 128;
    const int E = in_sizes[1] / 2;
    const int B1 = ceil_div(N, 1024);
    const int nbins = (N + BINW - 1) >> BSHIFT;

    char* p = (char*)d_ws;
    unsigned short* A = (unsigned short*)p; p += (size_t)N * HID * 2;  // bf16 gather table
    float* Bb     = (float*)p; p += (size_t)N * HID * 4;
    int2*  binned = (int2*)p;  p += (size_t)E * 8;
    int*   col    = (int*)p;   p += (size_t)E * 4;
    float* dinv   = (float*)p; p += (size_t)N * 4;
    int*   rs     = (int*)p;   p += (size_t)N * 4;
    int*   deg    = (int*)p;   p += (size_t)N * 4;
    int*   bsum   = (int*)p;   p += (size_t)((B1 + 1) & ~1) * 4;
    int*   binBase= (int*)p;   p += (NBINMAX + 2) * 4;
    // zeroed region: binCnt | binCur
    int*   binCnt = (int*)p;   p += NBINMAX * 4;
    int*   binCur = (int*)p;   p += NBINMAX * 4;

    hipMemsetAsync(binCnt, 0, 2 * NBINMAX * 4, stream);

    k_count<<<ceil_div(E, CHUNK), 256, 0, stream>>>(ei + E, binCnt, E, nbins);
    k_binoff<<<1, 256, 0, stream>>>(binCnt, binBase, nbins, E);
    k_bin<<<ceil_div(E, CHUNK), 256, 0, stream>>>(ei, ei + E, binBase, binCur, binned, E, nbins);
    k_hist<<<nbins, 256, 0, stream>>>(binned, binBase, deg, N);
    k_scan1<<<B1, 256, 0, stream>>>(deg, bsum, N);
    k_scan2<<<1, 256, 0, stream>>>(bsum, B1);
    k_scan3<<<B1, 256, 0, stream>>>(deg, bsum, rs, dinv, N);
    k_fillc<<<nbins, 256, 0, stream>>>(binned, binBase, rs, col, N);

    k_gemm<128><<<ceil_div(N, 64), 256, 0, stream>>>(x, W1, A, N);
    k_agg<<<ceil_div(N * 16, 256), 256, 0, stream>>>(A, Bb, rs, deg, col, dinv, b1, N, 1);
    k_gemm<64><<<ceil_div(N, 64), 256, 0, stream>>>(Bb, W2, A, N);
    k_agg<<<ceil_div(N * 16, 256), 256, 0, stream>>>(A, Bb, rs, deg, col, dinv, b2, N, 1);
    k_gemm<64><<<ceil_div(N, 64), 256, 0, stream>>>(Bb, W3, A, N);
    k_agg<<<ceil_div(N * 16, 256), 256, 0, stream>>>(A, Bb, rs, deg, col, dinv, b3, N, 0);

    k_pool_head<<<1024, 256, 0, stream>>>(Bb, bat, cent, rb, out, N);
}